// Round 5
// baseline (940.224 us; speedup 1.0000x reference)
//
#include <hip/hip_runtime.h>
#include <cstddef>

// ---------------- problem constants ----------------
constexpr int Gn = 4096;
constexpr int Un = 100000;
constexpr int In = 8192;
constexpr int Fd = 128;
constexpr int Mn = 8192;
constexpr int NNZ_RUI = 500000;
constexpr int NNZ_RGU = 8192;
constexpr int NNZ_RGI = 200000;
constexpr int NCH = 8;  // attention i-chunks / partial slabs

// CSR segment table: 0=rui_row 1=rui_col 2=rgu_row 3=rgu_col 4=rgi_row 5=rgi_col
constexpr int SEGL[6] = {Un + 1, In + 1, Gn + 1, Un + 1, Gn + 1, In + 1};
constexpr int segoff(int s) { int o = 0; for (int i = 0; i < s; ++i) o += SEGL[i]; return o; }
constexpr int CNT_TOT = segoff(6);
constexpr int EN[6] = {NNZ_RUI, NNZ_RUI, NNZ_RGU, NNZ_RGU, NNZ_RGI, NNZ_RGI};
constexpr int eoff(int s) { int o = 0; for (int i = 0; i < s; ++i) o += EN[i]; return o; }
constexpr int E_TOT = eoff(6);
constexpr int SCAN_BLK = 2048;
constexpr int MAXNB = (Un + 1 + SCAN_BLK - 1) / SCAN_BLK;  // 49

typedef __attribute__((ext_vector_type(8))) short s8b;
typedef __attribute__((ext_vector_type(4))) short s4b;
typedef __attribute__((ext_vector_type(4))) float f4b;

__device__ __forceinline__ float b2f(short s) {
  union { unsigned u; float f; } v;
  v.u = ((unsigned)(unsigned short)s) << 16;
  return v.f;
}
__device__ __forceinline__ short f2b(float x) {
  union { float f; unsigned u; } v;
  v.f = x;
  unsigned r = (v.u + 0x7fffu + ((v.u >> 16) & 1u)) >> 16;  // RNE
  return (short)r;
}

// ---------------- zero helper ----------------
__global__ void zero_i4(int* __restrict__ p, int n4) {
  int i = blockIdx.x * blockDim.x + threadIdx.x;
  if (i < n4) ((int4*)p)[i] = make_int4(0, 0, 0, 0);
}

// ---------------- f32 -> bf16 convert ----------------
__global__ void cvt_kernel(const float* __restrict__ in, short* __restrict__ out, int n) {
  int i = blockIdx.x * blockDim.x + threadIdx.x;
  if (i < n) out[i] = f2b(in[i]);
}

// ---------------- members gather + convert to bf16 ----------------
__global__ void gather_members(const float* __restrict__ ue, const int* __restrict__ idx,
                               short* __restrict__ mem) {
  int m = blockIdx.x;
  int u = idx[m];
  mem[m * Fd + threadIdx.x] = f2b(ue[(size_t)u * Fd + threadIdx.x]);
}

// ---------------- CSR build ----------------
__global__ void hist_kernel(const int* __restrict__ key, int* __restrict__ cnt, int nnz) {
  int e = blockIdx.x * 256 + threadIdx.x;
  if (e < nnz) atomicAdd(&cnt[key[e]], 1);
}

__global__ __launch_bounds__(256) void scanA(const int* __restrict__ cnt, int* __restrict__ ptr,
                                             int* __restrict__ bsum) {
  const int lens[6] = {Un + 1, In + 1, Gn + 1, Un + 1, Gn + 1, In + 1};
  int s = blockIdx.y;
  int len = lens[s];
  int off = 0;
#pragma unroll
  for (int i = 0; i < 6; ++i) if (i < s) off += lens[i];
  int b = blockIdx.x;
  int base = b * SCAN_BLK;
  if (base >= len) return;
  int tid = threadIdx.x;
  int i0 = base + tid * 8;
  int v[8], tsum = 0;
#pragma unroll
  for (int j = 0; j < 8; ++j) {
    int i = i0 + j;
    v[j] = (i < len) ? cnt[off + i] : 0;
    tsum += v[j];
  }
  __shared__ int sd[256];
  sd[tid] = tsum;
  __syncthreads();
  for (int o = 1; o < 256; o <<= 1) {
    int t = (tid >= o) ? sd[tid - o] : 0;
    __syncthreads();
    sd[tid] += t;
    __syncthreads();
  }
  int ex = sd[tid] - tsum;
#pragma unroll
  for (int j = 0; j < 8; ++j) {
    int i = i0 + j;
    if (i < len) ptr[off + i] = ex;
    ex += v[j];
  }
  if (tid == 255) bsum[s * 64 + b] = sd[255];
}

__global__ void scanB(int* __restrict__ bsum) {
  int s = blockIdx.x, t = threadIdx.x;  // 64 threads
  int v = bsum[s * 64 + t];
  int x = v;
#pragma unroll
  for (int o = 1; o < 64; o <<= 1) {
    int y = __shfl_up(x, o, 64);
    if (t >= o) x += y;
  }
  bsum[s * 64 + t] = x - v;
}

__global__ __launch_bounds__(256) void scanC(int* __restrict__ ptr, int* __restrict__ cursor,
                                             const int* __restrict__ bsum) {
  const int lens[6] = {Un + 1, In + 1, Gn + 1, Un + 1, Gn + 1, In + 1};
  int s = blockIdx.y;
  int len = lens[s];
  int off = 0;
#pragma unroll
  for (int i = 0; i < 6; ++i) if (i < s) off += lens[i];
  int b = blockIdx.x;
  int base = b * SCAN_BLK;
  if (base >= len) return;
  int add = bsum[s * 64 + b];
  int i0 = base + threadIdx.x * 8;
#pragma unroll
  for (int j = 0; j < 8; ++j) {
    int i = i0 + j;
    if (i < len) {
      int val = ptr[off + i] + add;
      ptr[off + i] = val;
      cursor[off + i] = val;
    }
  }
}

__global__ void scatter_kernel(const int* __restrict__ key, const int* __restrict__ gidx,
                               const float* __restrict__ vals, int* __restrict__ cursor,
                               int2* __restrict__ packed, int nnz) {
  int e = blockIdx.x * 256 + threadIdx.x;
  if (e >= nnz) return;
  int k = key[e];
  int pos = atomicAdd(&cursor[k], 1);
  union { float f; int i; } u;
  u.f = vals[e];
  packed[pos] = make_int2(gidx[e], u.i);
}

// ---------------- CSR SpMM: one wave per output row, no atomics ----------------
__global__ __launch_bounds__(256) void spmm_csr_kernel(
    const int* __restrict__ ptr, const int2* __restrict__ packed,
    const float* __restrict__ x, float* __restrict__ out, int n) {
  int r = blockIdx.x * 4 + (threadIdx.x >> 6);
  if (r >= n) return;
  int lane = threadIdx.x & 63;
  int s = ptr[r], e = ptr[r + 1];
  float a0 = 0.f, a1 = 0.f;
  for (int j = s; j < e; ++j) {
    int2 ed = packed[j];
    union { int i; float f; } u;
    u.i = ed.y;
    const float* xp = x + (size_t)ed.x * Fd + lane * 2;
    a0 += u.f * xp[0];
    a1 += u.f * xp[1];
  }
  *(float2*)(out + (size_t)r * Fd + lane * 2) = make_float2(a0, a1);
}

// ---------------- attention pass A: partial colsum, no atomics ----------------
__global__ __launch_bounds__(256) void attn_colsum_kernel(
    const short* __restrict__ item, const short* __restrict__ mem,
    float* __restrict__ part_cs) {
  int m0 = blockIdx.x * 128, ic = blockIdx.y;
  int tid = threadIdx.x;
  int wave = tid >> 6, lane = tid & 63, wc = wave >> 1;
  int lrow = lane & 15, quad = lane >> 4;
  __shared__ float cs[128];
  if (tid < 128) cs[tid] = 0.f;
  __syncthreads();
  f4b fz = {0.f, 0.f, 0.f, 0.f};
  float ps[4] = {0.f, 0.f, 0.f, 0.f};
  int wr = wave & 1;
  for (int it = 0; it < 8; ++it) {
    int i0 = ic * 1024 + it * 128;
    f4b acc[4][4];
#pragma unroll
    for (int rf = 0; rf < 4; ++rf)
#pragma unroll
      for (int cf = 0; cf < 4; ++cf) acc[rf][cf] = fz;
#pragma unroll
    for (int ks = 0; ks < 4; ++ks) {
      s8b a[4], b[4];
#pragma unroll
      for (int rf = 0; rf < 4; ++rf)
        a[rf] = *(const s8b*)(item + (size_t)(i0 + wr * 64 + rf * 16 + lrow) * Fd + ks * 32 + quad * 8);
#pragma unroll
      for (int cf = 0; cf < 4; ++cf)
        b[cf] = *(const s8b*)(mem + (size_t)(m0 + wc * 64 + cf * 16 + lrow) * Fd + ks * 32 + quad * 8);
#pragma unroll
      for (int rf = 0; rf < 4; ++rf)
#pragma unroll
        for (int cf = 0; cf < 4; ++cf)
          acc[rf][cf] = __builtin_amdgcn_mfma_f32_16x16x32_bf16(a[rf], b[cf], acc[rf][cf], 0, 0, 0);
    }
#pragma unroll
    for (int cf = 0; cf < 4; ++cf)
#pragma unroll
      for (int rf = 0; rf < 4; ++rf)
#pragma unroll
        for (int r = 0; r < 4; ++r) ps[cf] += __expf(acc[rf][cf][r]);
  }
#pragma unroll
  for (int cf = 0; cf < 4; ++cf) {
    float v = ps[cf];
    v += __shfl_xor(v, 16, 64);
    v += __shfl_xor(v, 32, 64);
    if (quad == 0) atomicAdd(&cs[wc * 64 + cf * 16 + lrow], v);
  }
  __syncthreads();
  if (tid < 128) part_cs[ic * Mn + m0 + tid] = cs[tid];
}

// ---------------- MT[f][m] = mem[m][f] / colsum[m] (bf16, 128 x 8192) ----------------
__global__ void mt_build(const short* __restrict__ mem, const float* __restrict__ part_cs,
                         short* __restrict__ MT) {
  int m = blockIdx.x * 64 + (threadIdx.x & 63);
  int w = threadIdx.x >> 6;
  float s = 0.f;
#pragma unroll
  for (int c = 0; c < NCH; ++c) s += part_cs[c * Mn + m];
  float inv = 1.0f / s;
#pragma unroll
  for (int it = 0; it < 4; ++it) {
    int oct = it * 4 + w;  // 0..15 (f octet)
    s8b v = *(const s8b*)(mem + (size_t)m * Fd + oct * 8);
#pragma unroll
    for (int j = 0; j < 8; ++j)
      MT[(size_t)(oct * 8 + j) * Mn + m] = f2b(b2f(v[j]) * inv);
  }
}

// ---------------- attention pass B: part[by] = exp(E) @ MT-chunk ----------------
__global__ __launch_bounds__(256, 2) void attn_out_kernel(
    const short* __restrict__ item, const short* __restrict__ mem,
    const short* __restrict__ MT, float* __restrict__ part) {
  __shared__ short P[128 * 72];
  int i0 = blockIdx.x * 128, by = blockIdx.y;
  int tid = threadIdx.x;
  int wave = tid >> 6, lane = tid & 63, wr = wave & 1, wc = wave >> 1;
  int lrow = lane & 15, quad = lane >> 4;
  f4b fz = {0.f, 0.f, 0.f, 0.f};

  s8b a[4][4];
#pragma unroll
  for (int ks = 0; ks < 4; ++ks)
#pragma unroll
    for (int rf = 0; rf < 4; ++rf)
      a[ks][rf] = *(const s8b*)(item + (size_t)(i0 + wr * 64 + rf * 16 + lrow) * Fd + ks * 32 + quad * 8);

  f4b oacc[4][4];
#pragma unroll
  for (int rf = 0; rf < 4; ++rf)
#pragma unroll
    for (int cf = 0; cf < 4; ++cf) oacc[rf][cf] = fz;

  for (int mt = 0; mt < 16; ++mt) {
    int m0 = by * 1024 + mt * 64;
    f4b eacc[4][2];
#pragma unroll
    for (int rf = 0; rf < 4; ++rf)
#pragma unroll
      for (int cf = 0; cf < 2; ++cf) eacc[rf][cf] = fz;
#pragma unroll
    for (int ks = 0; ks < 4; ++ks) {
      s8b b[2];
#pragma unroll
      for (int cf = 0; cf < 2; ++cf)
        b[cf] = *(const s8b*)(mem + (size_t)(m0 + wc * 32 + cf * 16 + lrow) * Fd + ks * 32 + quad * 8);
#pragma unroll
      for (int rf = 0; rf < 4; ++rf)
#pragma unroll
        for (int cf = 0; cf < 2; ++cf)
          eacc[rf][cf] = __builtin_amdgcn_mfma_f32_16x16x32_bf16(a[ks][rf], b[cf], eacc[rf][cf], 0, 0, 0);
    }
    __syncthreads();
#pragma unroll
    for (int cf = 0; cf < 2; ++cf) {
      int mcol = wc * 32 + cf * 16 + lrow;
#pragma unroll
      for (int rf = 0; rf < 4; ++rf)
#pragma unroll
        for (int r = 0; r < 4; ++r)
          P[(wr * 64 + rf * 16 + quad * 4 + r) * 72 + mcol] = f2b(__expf(eacc[rf][cf][r]));
    }
    __syncthreads();
#pragma unroll
    for (int ks = 0; ks < 2; ++ks) {
      s8b pa[4], b[4];
#pragma unroll
      for (int rf = 0; rf < 4; ++rf)
        pa[rf] = *(const s8b*)&P[(wr * 64 + rf * 16 + lrow) * 72 + ks * 32 + quad * 8];
#pragma unroll
      for (int cf = 0; cf < 4; ++cf)
        b[cf] = *(const s8b*)(MT + (size_t)(wc * 64 + cf * 16 + lrow) * Mn + m0 + ks * 32 + quad * 8);
#pragma unroll
      for (int rf = 0; rf < 4; ++rf)
#pragma unroll
        for (int cf = 0; cf < 4; ++cf)
          oacc[rf][cf] = __builtin_amdgcn_mfma_f32_16x16x32_bf16(pa[rf], b[cf], oacc[rf][cf], 0, 0, 0);
    }
  }
  float* slab = part + (size_t)by * In * Fd;
#pragma unroll
  for (int cf = 0; cf < 4; ++cf) {
    int col = wc * 64 + cf * 16 + lrow;
#pragma unroll
    for (int rf = 0; rf < 4; ++rf)
#pragma unroll
      for (int r = 0; r < 4; ++r) {
        int row = wr * 64 + rf * 16 + quad * 4 + r;
        slab[(size_t)(i0 + row) * Fd + col] = oacc[rf][cf][r];
      }
  }
}

// ---------------- att_item = (sum of partials) * item ----------------
__global__ void reduce_mul_kernel(const float* __restrict__ part, const float* __restrict__ item,
                                  float* __restrict__ out) {
  int i = blockIdx.x * 256 + threadIdx.x;  // f4 index
  f4b s = {0.f, 0.f, 0.f, 0.f};
#pragma unroll
  for (int c = 0; c < NCH; ++c) {
    f4b v = ((const f4b*)(part + (size_t)c * In * Fd))[i];
    s[0] += v[0]; s[1] += v[1]; s[2] += v[2]; s[3] += v[3];
  }
  f4b it = ((const f4b*)item)[i];
  s[0] *= it[0]; s[1] *= it[1]; s[2] *= it[2]; s[3] *= it[3];
  ((f4b*)out)[i] = s;
}

// ---------------- fused lin5 + bias + LeakyReLU + row L2-norm (f32 I/O) ----------------
// LDS = bf16 stage only (34.8 KB) -> 3 blocks/CU; epilogue stores direct from regs.
template <int PAT>
__global__ __launch_bounds__(256, 3) void lin5_kernel(
    const float* __restrict__ x, const float* __restrict__ A,
    const float* __restrict__ B, const float* __restrict__ C,
    const short* __restrict__ W, const float* __restrict__ bias,
    float* __restrict__ out, int N) {
  __shared__ __align__(16) short Xs[128 * 136];
  __shared__ float bsum[128];
  __shared__ float rs[128];
  int tid = threadIdx.x;
  int n0 = blockIdx.x * 128;
  int wave = tid >> 6, lane = tid & 63, wr = wave & 1, wc = wave >> 1;
  int lrow = lane & 15, quad = lane >> 4;
  if (tid < 128) {
    float s = 0.f;
#pragma unroll
    for (int k = 0; k < 5; ++k) s += bias[k * Fd + tid];
    bsum[tid] = s;
    rs[tid] = 0.f;
  }
  f4b acc[4][4];
  f4b fz = {0.f, 0.f, 0.f, 0.f};
#pragma unroll
  for (int rf = 0; rf < 4; ++rf)
#pragma unroll
    for (int cf = 0; cf < 4; ++cf) acc[rf][cf] = fz;

  const bool full = (n0 + 128 <= N);

#pragma unroll
  for (int seg = 0; seg < 5; ++seg) {
    __syncthreads();
    // build X segment (128 x 128 bf16) in LDS
#pragma unroll
    for (int it = 0; it < 16; ++it) {
      int flat = (it * 256 + tid) * 4;
      int r = flat >> 7, f = flat & 127;
      int n = n0 + r;
      s4b o = {0, 0, 0, 0};
      if (full || n < N) {
        if (seg == 0) {
          f4b xv = *(const f4b*)(x + (size_t)n * Fd + f);
          o[0] = f2b(xv[0]); o[1] = f2b(xv[1]); o[2] = f2b(xv[2]); o[3] = f2b(xv[3]);
        } else {
          const float* S;
          bool mx;
          if (PAT == 0) {
            S = (seg <= 2) ? A : B;
            mx = (seg == 2 || seg == 3);
          } else {
            S = (seg == 1 || seg == 3) ? A : ((seg == 2) ? B : C);
            mx = (seg == 2 || seg == 3);
          }
          f4b v = *(const f4b*)(S + (size_t)n * Fd + f);
          if (mx) {
            f4b xv = *(const f4b*)(x + (size_t)n * Fd + f);
            v[0] *= xv[0]; v[1] *= xv[1]; v[2] *= xv[2]; v[3] *= xv[3];
          }
          o[0] = f2b(v[0]); o[1] = f2b(v[1]); o[2] = f2b(v[2]); o[3] = f2b(v[3]);
        }
      }
      *(s4b*)&Xs[r * 136 + f] = o;
    }
    __syncthreads();
    const short* Wseg = W + seg * Fd * Fd;
#pragma unroll
    for (int ks = 0; ks < 4; ++ks) {
      s8b bfr[4];
#pragma unroll
      for (int cf = 0; cf < 4; ++cf)
        bfr[cf] = *(const s8b*)(Wseg + (size_t)(wc * 64 + cf * 16 + lrow) * Fd + ks * 32 + quad * 8);
#pragma unroll
      for (int rf = 0; rf < 4; ++rf) {
        s8b afr = *(const s8b*)&Xs[(wr * 64 + rf * 16 + lrow) * 136 + ks * 32 + quad * 8];
#pragma unroll
        for (int cf = 0; cf < 4; ++cf)
          acc[rf][cf] = __builtin_amdgcn_mfma_f32_16x16x32_bf16(afr, bfr[cf], acc[rf][cf], 0, 0, 0);
      }
    }
  }
  // epilogue: bias + LeakyReLU in-place, per-row sum of squares
  float rp[4][4];
#pragma unroll
  for (int rf = 0; rf < 4; ++rf)
#pragma unroll
    for (int r = 0; r < 4; ++r) rp[rf][r] = 0.f;
#pragma unroll
  for (int cf = 0; cf < 4; ++cf) {
    int col = wc * 64 + cf * 16 + lrow;
    float bs = bsum[col];
#pragma unroll
    for (int rf = 0; rf < 4; ++rf)
#pragma unroll
      for (int r = 0; r < 4; ++r) {
        float v = acc[rf][cf][r] + bs;
        v = (v >= 0.f) ? v : 0.01f * v;
        acc[rf][cf][r] = v;
        rp[rf][r] += v * v;
      }
  }
  // butterfly over the 16-lane group (cols of this wave's half)
#pragma unroll
  for (int m = 1; m < 16; m <<= 1)
#pragma unroll
    for (int rf = 0; rf < 4; ++rf)
#pragma unroll
      for (int r = 0; r < 4; ++r) rp[rf][r] += __shfl_xor(rp[rf][r], m, 64);
  if (lrow == 0) {
#pragma unroll
    for (int rf = 0; rf < 4; ++rf)
#pragma unroll
      for (int r = 0; r < 4; ++r)
        atomicAdd(&rs[wr * 64 + rf * 16 + quad * 4 + r], rp[rf][r]);
  }
  __syncthreads();
  // normalize + store direct from registers (16-lane x 4B = 64B coalesced segments)
#pragma unroll
  for (int rf = 0; rf < 4; ++rf)
#pragma unroll
    for (int r = 0; r < 4; ++r) {
      int row = wr * 64 + rf * 16 + quad * 4 + r;
      int n = n0 + row;
      if (full || n < N) {
        float sc = 1.0f / fmaxf(sqrtf(rs[row]), 1e-12f);
#pragma unroll
        for (int cf = 0; cf < 4; ++cf) {
          int col = wc * 64 + cf * 16 + lrow;
          out[(size_t)n * Fd + col] = acc[rf][cf][r] * sc;
        }
      }
    }
}

// ---------------- launch ----------------
extern "C" void kernel_launch(void* const* d_in, const int* in_sizes, int n_in,
                              void* d_out, int out_size, void* d_ws, size_t ws_size,
                              hipStream_t stream) {
  const float* group_emb = (const float*)d_in[0];
  const float* user_emb  = (const float*)d_in[1];
  const float* item_emb  = (const float*)d_in[2];
  const int* member_idx  = (const int*)d_in[3];
  const int* rui_rows = (const int*)d_in[4];
  const int* rui_cols = (const int*)d_in[5];
  const float* rui_vals = (const float*)d_in[6];
  const int* rgu_rows = (const int*)d_in[7];
  const int* rgu_cols = (const int*)d_in[8];
  const float* rgu_vals = (const float*)d_in[9];
  const int* rgi_rows = (const int*)d_in[10];
  const int* rgi_cols = (const int*)d_in[11];
  const float* rgi_vals = (const float*)d_in[12];
  const float* Wu = (const float*)d_in[13];
  const float* bu = (const float*)d_in[14];
  const float* Wi = (const float*)d_in[15];
  const float* bi = (const float*)d_in[16];
  const float* Wg = (const float*)d_in[17];
  const float* bg = (const float*)d_in[18];
  (void)in_sizes; (void)n_in; (void)out_size; (void)ws_size;

  float* ws = (float*)d_ws;
  float* e_rui_u = ws;                               // U*F
  float* e_rgu_u = e_rui_u + (size_t)Un * Fd;        // U*F
  float* e_rui_i = e_rgu_u + (size_t)Un * Fd;        // I*F
  float* e_rgi_i = e_rui_i + (size_t)In * Fd;        // I*F
  float* e_rgi_g = e_rgi_i + (size_t)In * Fd;        // G*F
  float* e_rgu_g = e_rgi_g + (size_t)Gn * Fd;        // G*F
  float* e_att_g = e_rgu_g + (size_t)Gn * Fd;        // G*F
  float* att_item = e_att_g + (size_t)Gn * Fd;       // I*F
  float* part_cs = att_item + (size_t)In * Fd;       // NCH*M
  short* members_bf = (short*)(part_cs + NCH * Mn);  // M*F bf16
  short* item_bf = members_bf + (size_t)Mn * Fd;     // I*F bf16
  short* MT = item_bf + (size_t)In * Fd;             // F*M bf16 (transposed scaled members)
  short* wu_bf = MT + (size_t)Fd * Mn;               // 5*F*F bf16
  short* wi_bf = wu_bf + 5 * Fd * Fd;
  short* wg_bf = wi_bf + 5 * Fd * Fd;
  int* cnt    = (int*)(wg_bf + 5 * Fd * Fd);         // CNT_TOT
  int* bsum   = cnt + CNT_TOT;                       // 6*64
  int* ptr    = bsum + 6 * 64;                       // CNT_TOT
  int* cursor = ptr + CNT_TOT;                       // CNT_TOT
  int2* packed = (int2*)(cursor + CNT_TOT);          // E_TOT

  // attention partial slabs alias d_out (fully overwritten by lin5 at the end)
  float* part_att = (float*)d_out;                   // NCH * I*F f32

  // zero cnt (+bsum)
  {
    int nz = CNT_TOT + 6 * 64;
    int n4 = (nz + 3) / 4;  // may spill into ptr (overwritten later)
    zero_i4<<<(n4 + 255) / 256, 256, 0, stream>>>(cnt, n4);
  }

  // bf16 conversions
  cvt_kernel<<<(In * Fd + 255) / 256, 256, 0, stream>>>(item_emb, item_bf, In * Fd);
  cvt_kernel<<<(5 * Fd * Fd + 255) / 256, 256, 0, stream>>>(Wu, wu_bf, 5 * Fd * Fd);
  cvt_kernel<<<(5 * Fd * Fd + 255) / 256, 256, 0, stream>>>(Wi, wi_bf, 5 * Fd * Fd);
  cvt_kernel<<<(5 * Fd * Fd + 255) / 256, 256, 0, stream>>>(Wg, wg_bf, 5 * Fd * Fd);
  gather_members<<<Mn, Fd, 0, stream>>>(user_emb, member_idx, members_bf);

  // histograms
  hist_kernel<<<(NNZ_RUI + 255) / 256, 256, 0, stream>>>(rui_rows, cnt + segoff(0), NNZ_RUI);
  hist_kernel<<<(NNZ_RUI + 255) / 256, 256, 0, stream>>>(rui_cols, cnt + segoff(1), NNZ_RUI);
  hist_kernel<<<(NNZ_RGU + 255) / 256, 256, 0, stream>>>(rgu_rows, cnt + segoff(2), NNZ_RGU);
  hist_kernel<<<(NNZ_RGU + 255) / 256, 256, 0, stream>>>(rgu_cols, cnt + segoff(3), NNZ_RGU);
  hist_kernel<<<(NNZ_RGI + 255) / 256, 256, 0, stream>>>(rgi_rows, cnt + segoff(4), NNZ_RGI);
  hist_kernel<<<(NNZ_RGI + 255) / 256, 256, 0, stream>>>(rgi_cols, cnt + segoff(5), NNZ_RGI);

  // batched exclusive scans -> row_ptr + cursor
  scanA<<<dim3(MAXNB, 6), 256, 0, stream>>>(cnt, ptr, bsum);
  scanB<<<6, 64, 0, stream>>>(bsum);
  scanC<<<dim3(MAXNB, 6), 256, 0, stream>>>(ptr, cursor, bsum);

  // scatter packed (gather_idx, val)
  scatter_kernel<<<(NNZ_RUI + 255) / 256, 256, 0, stream>>>(rui_rows, rui_cols, rui_vals, cursor + segoff(0), packed + eoff(0), NNZ_RUI);
  scatter_kernel<<<(NNZ_RUI + 255) / 256, 256, 0, stream>>>(rui_cols, rui_rows, rui_vals, cursor + segoff(1), packed + eoff(1), NNZ_RUI);
  scatter_kernel<<<(NNZ_RGU + 255) / 256, 256, 0, stream>>>(rgu_rows, rgu_cols, rgu_vals, cursor + segoff(2), packed + eoff(2), NNZ_RGU);
  scatter_kernel<<<(NNZ_RGU + 255) / 256, 256, 0, stream>>>(rgu_cols, rgu_rows, rgu_vals, cursor + segoff(3), packed + eoff(3), NNZ_RGU);
  scatter_kernel<<<(NNZ_RGI + 255) / 256, 256, 0, stream>>>(rgi_rows, rgi_cols, rgi_vals, cursor + segoff(4), packed + eoff(4), NNZ_RGI);
  scatter_kernel<<<(NNZ_RGI + 255) / 256, 256, 0, stream>>>(rgi_cols, rgi_rows, rgi_vals, cursor + segoff(5), packed + eoff(5), NNZ_RGI);

  // CSR SpMMs
  spmm_csr_kernel<<<(Un + 3) / 4, 256, 0, stream>>>(ptr + segoff(0), packed + eoff(0), item_emb, e_rui_u, Un);
  spmm_csr_kernel<<<(Un + 3) / 4, 256, 0, stream>>>(ptr + segoff(3), packed + eoff(3), group_emb, e_rgu_u, Un);
  spmm_csr_kernel<<<(In + 3) / 4, 256, 0, stream>>>(ptr + segoff(1), packed + eoff(1), user_emb, e_rui_i, In);
  spmm_csr_kernel<<<(In + 3) / 4, 256, 0, stream>>>(ptr + segoff(5), packed + eoff(5), group_emb, e_rgi_i, In);
  spmm_csr_kernel<<<(Gn + 3) / 4, 256, 0, stream>>>(ptr + segoff(4), packed + eoff(4), item_emb, e_rgi_g, Gn);
  spmm_csr_kernel<<<(Gn + 3) / 4, 256, 0, stream>>>(ptr + segoff(2), packed + eoff(2), user_emb, e_rgu_g, Gn);

  // attention: partial colsum -> scaled transpose -> PV with global MT
  attn_colsum_kernel<<<dim3(Mn / 128, NCH), 256, 0, stream>>>(item_bf, members_bf, part_cs);
  mt_build<<<Mn / 64, 256, 0, stream>>>(members_bf, part_cs, MT);
  attn_out_kernel<<<dim3(In / 128, NCH), 256, 0, stream>>>(item_bf, members_bf, MT, part_att);
  reduce_mul_kernel<<<(In * Fd / 4) / 256, 256, 0, stream>>>(part_att, item_emb, att_item);
  spmm_csr_kernel<<<(Gn + 3) / 4, 256, 0, stream>>>(ptr + segoff(4), packed + eoff(4), att_item, e_att_g, Gn);

  // fused lin5 + LeakyReLU + L2 norm; output order: group | user | item
  float* out_g = (float*)d_out;
  float* out_u = out_g + (size_t)Gn * Fd;
  float* out_i = out_u + (size_t)Un * Fd;
  lin5_kernel<1><<<Gn / 128, 256, 0, stream>>>(group_emb, e_rgi_g, e_rgu_g, e_att_g, wg_bf, bg, out_g, Gn);
  lin5_kernel<0><<<(Un + 127) / 128, 256, 0, stream>>>(user_emb, e_rui_u, e_rgu_u, nullptr, wu_bf, bu, out_u, Un);
  lin5_kernel<0><<<In / 128, 256, 0, stream>>>(item_emb, e_rui_i, e_rgi_i, nullptr, wi_bf, bi, out_i, In);
}

// Round 6
// 843.156 us; speedup vs baseline: 1.1151x; 1.1151x over previous
//
#include <hip/hip_runtime.h>
#include <cstddef>

// ---------------- problem constants ----------------
constexpr int Gn = 4096;
constexpr int Un = 100000;
constexpr int In = 8192;
constexpr int Fd = 128;
constexpr int Mn = 8192;
constexpr int NNZ_RUI = 500000;
constexpr int NNZ_RGU = 8192;
constexpr int NNZ_RGI = 200000;
constexpr int NCH = 8;  // attention i-chunks / partial slabs

// CSR segment table: 0=rui_row 1=rui_col 2=rgu_row 3=rgu_col 4=rgi_row 5=rgi_col
constexpr int SEGL[6] = {Un + 1, In + 1, Gn + 1, Un + 1, Gn + 1, In + 1};
constexpr int segoff(int s) { int o = 0; for (int i = 0; i < s; ++i) o += SEGL[i]; return o; }
constexpr int CNT_TOT = segoff(6);
constexpr int EN[6] = {NNZ_RUI, NNZ_RUI, NNZ_RGU, NNZ_RGU, NNZ_RGI, NNZ_RGI};
constexpr int eoff(int s) { int o = 0; for (int i = 0; i < s; ++i) o += EN[i]; return o; }
constexpr int E_TOT = eoff(6);
constexpr int SCAN_BLK = 2048;
constexpr int MAXNB = (Un + 1 + SCAN_BLK - 1) / SCAN_BLK;  // 49

typedef __attribute__((ext_vector_type(8))) short s8b;
typedef __attribute__((ext_vector_type(4))) short s4b;
typedef __attribute__((ext_vector_type(4))) float f4b;

__device__ __forceinline__ float b2f(short s) {
  union { unsigned u; float f; } v;
  v.u = ((unsigned)(unsigned short)s) << 16;
  return v.f;
}
__device__ __forceinline__ short f2b(float x) {
  union { float f; unsigned u; } v;
  v.f = x;
  unsigned r = (v.u + 0x7fffu + ((v.u >> 16) & 1u)) >> 16;  // RNE
  return (short)r;
}

// ---------------- zero helper ----------------
__global__ void zero_i4(int* __restrict__ p, int n4) {
  int i = blockIdx.x * blockDim.x + threadIdx.x;
  if (i < n4) ((int4*)p)[i] = make_int4(0, 0, 0, 0);
}

// ---------------- f32 -> bf16 convert ----------------
__global__ void cvt_kernel(const float* __restrict__ in, short* __restrict__ out, int n) {
  int i = blockIdx.x * blockDim.x + threadIdx.x;
  if (i < n) out[i] = f2b(in[i]);
}

// ---------------- members gather (bf16 copy) ----------------
__global__ void gather_members(const short* __restrict__ ub, const int* __restrict__ idx,
                               short* __restrict__ mem) {
  int m = blockIdx.x;
  int u = idx[m];
  mem[m * Fd + threadIdx.x] = ub[(size_t)u * Fd + threadIdx.x];
}

// ---------------- CSR build ----------------
__global__ void hist_kernel(const int* __restrict__ key, int* __restrict__ cnt, int nnz) {
  int e = blockIdx.x * 256 + threadIdx.x;
  if (e < nnz) atomicAdd(&cnt[key[e]], 1);
}

__global__ __launch_bounds__(256) void scanA(const int* __restrict__ cnt, int* __restrict__ ptr,
                                             int* __restrict__ bsum) {
  const int lens[6] = {Un + 1, In + 1, Gn + 1, Un + 1, Gn + 1, In + 1};
  int s = blockIdx.y;
  int len = lens[s];
  int off = 0;
#pragma unroll
  for (int i = 0; i < 6; ++i) if (i < s) off += lens[i];
  int b = blockIdx.x;
  int base = b * SCAN_BLK;
  if (base >= len) return;
  int tid = threadIdx.x;
  int i0 = base + tid * 8;
  int v[8], tsum = 0;
#pragma unroll
  for (int j = 0; j < 8; ++j) {
    int i = i0 + j;
    v[j] = (i < len) ? cnt[off + i] : 0;
    tsum += v[j];
  }
  __shared__ int sd[256];
  sd[tid] = tsum;
  __syncthreads();
  for (int o = 1; o < 256; o <<= 1) {
    int t = (tid >= o) ? sd[tid - o] : 0;
    __syncthreads();
    sd[tid] += t;
    __syncthreads();
  }
  int ex = sd[tid] - tsum;
#pragma unroll
  for (int j = 0; j < 8; ++j) {
    int i = i0 + j;
    if (i < len) ptr[off + i] = ex;
    ex += v[j];
  }
  if (tid == 255) bsum[s * 64 + b] = sd[255];
}

__global__ void scanB(int* __restrict__ bsum) {
  int s = blockIdx.x, t = threadIdx.x;  // 64 threads
  int v = bsum[s * 64 + t];
  int x = v;
#pragma unroll
  for (int o = 1; o < 64; o <<= 1) {
    int y = __shfl_up(x, o, 64);
    if (t >= o) x += y;
  }
  bsum[s * 64 + t] = x - v;
}

__global__ __launch_bounds__(256) void scanC(int* __restrict__ ptr, int* __restrict__ cursor,
                                             const int* __restrict__ bsum) {
  const int lens[6] = {Un + 1, In + 1, Gn + 1, Un + 1, Gn + 1, In + 1};
  int s = blockIdx.y;
  int len = lens[s];
  int off = 0;
#pragma unroll
  for (int i = 0; i < 6; ++i) if (i < s) off += lens[i];
  int b = blockIdx.x;
  int base = b * SCAN_BLK;
  if (base >= len) return;
  int add = bsum[s * 64 + b];
  int i0 = base + threadIdx.x * 8;
#pragma unroll
  for (int j = 0; j < 8; ++j) {
    int i = i0 + j;
    if (i < len) {
      int val = ptr[off + i] + add;
      ptr[off + i] = val;
      cursor[off + i] = val;
    }
  }
}

__global__ void scatter_kernel(const int* __restrict__ key, const int* __restrict__ gidx,
                               const float* __restrict__ vals, int* __restrict__ cursor,
                               int2* __restrict__ packed, int nnz) {
  int e = blockIdx.x * 256 + threadIdx.x;
  if (e >= nnz) return;
  int k = key[e];
  int pos = atomicAdd(&cursor[k], 1);
  union { float f; int i; } u;
  u.f = vals[e];
  packed[pos] = make_int2(gidx[e], u.i);
}

// ---------------- CSR SpMM: bf16 gather, f32 accumulate, bf16 row write ----------------
__global__ __launch_bounds__(256) void spmm_csr_kernel(
    const int* __restrict__ ptr, const int2* __restrict__ packed,
    const short* __restrict__ x, short* __restrict__ out, int n) {
  int r = blockIdx.x * 4 + (threadIdx.x >> 6);
  if (r >= n) return;
  int lane = threadIdx.x & 63;
  int s = ptr[r], e = ptr[r + 1];
  float a0 = 0.f, a1 = 0.f;
  for (int j = s; j < e; ++j) {
    int2 ed = packed[j];
    union { int i; float f; } u;
    u.i = ed.y;
    unsigned xv = *(const unsigned*)(x + (size_t)ed.x * Fd + lane * 2);
    a0 += u.f * b2f((short)(xv & 0xffffu));
    a1 += u.f * b2f((short)(xv >> 16));
  }
  unsigned o = ((unsigned)(unsigned short)f2b(a0)) | (((unsigned)(unsigned short)f2b(a1)) << 16);
  *(unsigned*)(out + (size_t)r * Fd + lane * 2) = o;
}

// ---------------- attention pass A: partial colsum, no atomics ----------------
__global__ __launch_bounds__(256) void attn_colsum_kernel(
    const short* __restrict__ item, const short* __restrict__ mem,
    float* __restrict__ part_cs) {
  int m0 = blockIdx.x * 128, ic = blockIdx.y;
  int tid = threadIdx.x;
  int wave = tid >> 6, lane = tid & 63, wc = wave >> 1;
  int lrow = lane & 15, quad = lane >> 4;
  __shared__ float cs[128];
  if (tid < 128) cs[tid] = 0.f;
  __syncthreads();
  f4b fz = {0.f, 0.f, 0.f, 0.f};
  float ps[4] = {0.f, 0.f, 0.f, 0.f};
  int wr = wave & 1;
  for (int it = 0; it < 8; ++it) {
    int i0 = ic * 1024 + it * 128;
    f4b acc[4][4];
#pragma unroll
    for (int rf = 0; rf < 4; ++rf)
#pragma unroll
      for (int cf = 0; cf < 4; ++cf) acc[rf][cf] = fz;
#pragma unroll
    for (int ks = 0; ks < 4; ++ks) {
      s8b a[4], b[4];
#pragma unroll
      for (int rf = 0; rf < 4; ++rf)
        a[rf] = *(const s8b*)(item + (size_t)(i0 + wr * 64 + rf * 16 + lrow) * Fd + ks * 32 + quad * 8);
#pragma unroll
      for (int cf = 0; cf < 4; ++cf)
        b[cf] = *(const s8b*)(mem + (size_t)(m0 + wc * 64 + cf * 16 + lrow) * Fd + ks * 32 + quad * 8);
#pragma unroll
      for (int rf = 0; rf < 4; ++rf)
#pragma unroll
        for (int cf = 0; cf < 4; ++cf)
          acc[rf][cf] = __builtin_amdgcn_mfma_f32_16x16x32_bf16(a[rf], b[cf], acc[rf][cf], 0, 0, 0);
    }
#pragma unroll
    for (int cf = 0; cf < 4; ++cf)
#pragma unroll
      for (int rf = 0; rf < 4; ++rf)
#pragma unroll
        for (int r = 0; r < 4; ++r) ps[cf] += __expf(acc[rf][cf][r]);
  }
#pragma unroll
  for (int cf = 0; cf < 4; ++cf) {
    float v = ps[cf];
    v += __shfl_xor(v, 16, 64);
    v += __shfl_xor(v, 32, 64);
    if (quad == 0) atomicAdd(&cs[wc * 64 + cf * 16 + lrow], v);
  }
  __syncthreads();
  if (tid < 128) part_cs[ic * Mn + m0 + tid] = cs[tid];
}

// ---------------- MT[f][m] = mem[m][f] / colsum[m] (bf16, 128 x 8192) ----------------
__global__ void mt_build(const short* __restrict__ mem, const float* __restrict__ part_cs,
                         short* __restrict__ MT) {
  int m = blockIdx.x * 64 + (threadIdx.x & 63);
  int w = threadIdx.x >> 6;
  float s = 0.f;
#pragma unroll
  for (int c = 0; c < NCH; ++c) s += part_cs[c * Mn + m];
  float inv = 1.0f / s;
#pragma unroll
  for (int it = 0; it < 4; ++it) {
    int oct = it * 4 + w;  // 0..15 (f octet)
    s8b v = *(const s8b*)(mem + (size_t)m * Fd + oct * 8);
#pragma unroll
    for (int j = 0; j < 8; ++j)
      MT[(size_t)(oct * 8 + j) * Mn + m] = f2b(b2f(v[j]) * inv);
  }
}

// ---------------- attention pass B: part[by] = exp(E) @ MT-chunk ----------------
__global__ __launch_bounds__(256, 2) void attn_out_kernel(
    const short* __restrict__ item, const short* __restrict__ mem,
    const short* __restrict__ MT, float* __restrict__ part) {
  __shared__ short P[128 * 72];
  int i0 = blockIdx.x * 128, by = blockIdx.y;
  int tid = threadIdx.x;
  int wave = tid >> 6, lane = tid & 63, wr = wave & 1, wc = wave >> 1;
  int lrow = lane & 15, quad = lane >> 4;
  f4b fz = {0.f, 0.f, 0.f, 0.f};

  s8b a[4][4];
#pragma unroll
  for (int ks = 0; ks < 4; ++ks)
#pragma unroll
    for (int rf = 0; rf < 4; ++rf)
      a[ks][rf] = *(const s8b*)(item + (size_t)(i0 + wr * 64 + rf * 16 + lrow) * Fd + ks * 32 + quad * 8);

  f4b oacc[4][4];
#pragma unroll
  for (int rf = 0; rf < 4; ++rf)
#pragma unroll
    for (int cf = 0; cf < 4; ++cf) oacc[rf][cf] = fz;

  for (int mt = 0; mt < 16; ++mt) {
    int m0 = by * 1024 + mt * 64;
    f4b eacc[4][2];
#pragma unroll
    for (int rf = 0; rf < 4; ++rf)
#pragma unroll
      for (int cf = 0; cf < 2; ++cf) eacc[rf][cf] = fz;
#pragma unroll
    for (int ks = 0; ks < 4; ++ks) {
      s8b b[2];
#pragma unroll
      for (int cf = 0; cf < 2; ++cf)
        b[cf] = *(const s8b*)(mem + (size_t)(m0 + wc * 32 + cf * 16 + lrow) * Fd + ks * 32 + quad * 8);
#pragma unroll
      for (int rf = 0; rf < 4; ++rf)
#pragma unroll
        for (int cf = 0; cf < 2; ++cf)
          eacc[rf][cf] = __builtin_amdgcn_mfma_f32_16x16x32_bf16(a[ks][rf], b[cf], eacc[rf][cf], 0, 0, 0);
    }
    __syncthreads();
#pragma unroll
    for (int cf = 0; cf < 2; ++cf) {
      int mcol = wc * 32 + cf * 16 + lrow;
#pragma unroll
      for (int rf = 0; rf < 4; ++rf)
#pragma unroll
        for (int r = 0; r < 4; ++r)
          P[(wr * 64 + rf * 16 + quad * 4 + r) * 72 + mcol] = f2b(__expf(eacc[rf][cf][r]));
    }
    __syncthreads();
#pragma unroll
    for (int ks = 0; ks < 2; ++ks) {
      s8b pa[4], b[4];
#pragma unroll
      for (int rf = 0; rf < 4; ++rf)
        pa[rf] = *(const s8b*)&P[(wr * 64 + rf * 16 + lrow) * 72 + ks * 32 + quad * 8];
#pragma unroll
      for (int cf = 0; cf < 4; ++cf)
        b[cf] = *(const s8b*)(MT + (size_t)(wc * 64 + cf * 16 + lrow) * Mn + m0 + ks * 32 + quad * 8);
#pragma unroll
      for (int rf = 0; rf < 4; ++rf)
#pragma unroll
        for (int cf = 0; cf < 4; ++cf)
          oacc[rf][cf] = __builtin_amdgcn_mfma_f32_16x16x32_bf16(pa[rf], b[cf], oacc[rf][cf], 0, 0, 0);
    }
  }
  float* slab = part + (size_t)by * In * Fd;
#pragma unroll
  for (int cf = 0; cf < 4; ++cf) {
    int col = wc * 64 + cf * 16 + lrow;
#pragma unroll
    for (int rf = 0; rf < 4; ++rf)
#pragma unroll
      for (int r = 0; r < 4; ++r) {
        int row = wr * 64 + rf * 16 + quad * 4 + r;
        slab[(size_t)(i0 + row) * Fd + col] = oacc[rf][cf][r];
      }
  }
}

// ---------------- att_item(bf16) = (sum of partials) * item(f32) ----------------
__global__ void reduce_mul_kernel(const float* __restrict__ part, const float* __restrict__ item,
                                  short* __restrict__ out) {
  int i = blockIdx.x * 256 + threadIdx.x;  // f4 index
  f4b s = {0.f, 0.f, 0.f, 0.f};
#pragma unroll
  for (int c = 0; c < NCH; ++c) {
    f4b v = ((const f4b*)(part + (size_t)c * In * Fd))[i];
    s[0] += v[0]; s[1] += v[1]; s[2] += v[2]; s[3] += v[3];
  }
  f4b it = ((const f4b*)item)[i];
  s4b o;
  o[0] = f2b(s[0] * it[0]); o[1] = f2b(s[1] * it[1]);
  o[2] = f2b(s[2] * it[2]); o[3] = f2b(s[3] * it[3]);
  ((s4b*)out)[i] = o;
}

// ---------------- fused lin5 + bias + LeakyReLU + row L2-norm ----------------
// All operands bf16 in global, A-frags loaded DIRECTLY from global (no LDS staging,
// no per-seg barriers); f32 out stored straight from registers.
// PAT 0 (user/item): segs = [x, A, A*x, B*x, B]
// PAT 1 (group):     segs = [x, A, B*x, A*x, C]
template <int PAT>
__global__ __launch_bounds__(256, 2) void lin5_kernel(
    const short* __restrict__ x, const short* __restrict__ A,
    const short* __restrict__ B, const short* __restrict__ C,
    const short* __restrict__ W, const float* __restrict__ bias,
    float* __restrict__ out, int N) {
  __shared__ float bsum[128];
  __shared__ float rs[128];
  int tid = threadIdx.x;
  int n0 = blockIdx.x * 128;
  int wave = tid >> 6, lane = tid & 63, wr = wave & 1, wc = wave >> 1;
  int lrow = lane & 15, quad = lane >> 4;
  if (tid < 128) {
    float s = 0.f;
#pragma unroll
    for (int k = 0; k < 5; ++k) s += bias[k * Fd + tid];
    bsum[tid] = s;
    rs[tid] = 0.f;
  }
  __syncthreads();  // rs/bsum visible before epilogue atomics
  f4b acc[4][4];
  f4b fz = {0.f, 0.f, 0.f, 0.f};
#pragma unroll
  for (int rf = 0; rf < 4; ++rf)
#pragma unroll
    for (int cf = 0; cf < 4; ++cf) acc[rf][cf] = fz;

  const bool full = (n0 + 128 <= N);
  // clamp row for frag loads in the partial tile (garbage rows never stored)
  int rbase = n0 + wr * 64 + lrow;

#pragma unroll
  for (int seg = 0; seg < 5; ++seg) {
    const short* S;
    bool mx;
    if (seg == 0) {
      S = x; mx = false;
    } else if (PAT == 0) {
      S = (seg <= 2) ? A : B;
      mx = (seg == 2 || seg == 3);
    } else {
      S = (seg == 1 || seg == 3) ? A : ((seg == 2) ? B : C);
      mx = (seg == 2 || seg == 3);
    }
    const short* Wseg = W + seg * Fd * Fd;
#pragma unroll
    for (int ks = 0; ks < 4; ++ks) {
      s8b bfr[4];
#pragma unroll
      for (int cf = 0; cf < 4; ++cf)
        bfr[cf] = *(const s8b*)(Wseg + (size_t)(wc * 64 + cf * 16 + lrow) * Fd + ks * 32 + quad * 8);
#pragma unroll
      for (int rf = 0; rf < 4; ++rf) {
        int row = rbase + rf * 16;
        if (!full && row >= N) row = N - 1;  // keep loads in-bounds
        size_t off = (size_t)row * Fd + ks * 32 + quad * 8;
        s8b afr = *(const s8b*)(S + off);
        if (mx) {
          s8b xf = *(const s8b*)(x + off);
#pragma unroll
          for (int j = 0; j < 8; ++j) afr[j] = f2b(b2f(afr[j]) * b2f(xf[j]));
        }
#pragma unroll
        for (int cf = 0; cf < 4; ++cf)
          acc[rf][cf] = __builtin_amdgcn_mfma_f32_16x16x32_bf16(afr, bfr[cf], acc[rf][cf], 0, 0, 0);
      }
    }
  }
  // epilogue: bias + LeakyReLU in-place, per-row sum of squares
  float rp[4][4];
#pragma unroll
  for (int rf = 0; rf < 4; ++rf)
#pragma unroll
    for (int r = 0; r < 4; ++r) rp[rf][r] = 0.f;
#pragma unroll
  for (int cf = 0; cf < 4; ++cf) {
    int col = wc * 64 + cf * 16 + lrow;
    float bs = bsum[col];
#pragma unroll
    for (int rf = 0; rf < 4; ++rf)
#pragma unroll
      for (int r = 0; r < 4; ++r) {
        float v = acc[rf][cf][r] + bs;
        v = (v >= 0.f) ? v : 0.01f * v;
        acc[rf][cf][r] = v;
        rp[rf][r] += v * v;
      }
  }
#pragma unroll
  for (int m = 1; m < 16; m <<= 1)
#pragma unroll
    for (int rf = 0; rf < 4; ++rf)
#pragma unroll
      for (int r = 0; r < 4; ++r) rp[rf][r] += __shfl_xor(rp[rf][r], m, 64);
  if (lrow == 0) {
#pragma unroll
    for (int rf = 0; rf < 4; ++rf)
#pragma unroll
      for (int r = 0; r < 4; ++r)
        atomicAdd(&rs[wr * 64 + rf * 16 + quad * 4 + r], rp[rf][r]);
  }
  __syncthreads();
  // normalize + store direct from registers (wave covers 256B contiguous per row)
#pragma unroll
  for (int rf = 0; rf < 4; ++rf)
#pragma unroll
    for (int r = 0; r < 4; ++r) {
      int row = wr * 64 + rf * 16 + quad * 4 + r;
      int n = n0 + row;
      if (full || n < N) {
        float sc = 1.0f / fmaxf(sqrtf(rs[row]), 1e-12f);
#pragma unroll
        for (int cf = 0; cf < 4; ++cf) {
          int col = wc * 64 + cf * 16 + lrow;
          out[(size_t)n * Fd + col] = acc[rf][cf][r] * sc;
        }
      }
    }
}

// ---------------- launch ----------------
extern "C" void kernel_launch(void* const* d_in, const int* in_sizes, int n_in,
                              void* d_out, int out_size, void* d_ws, size_t ws_size,
                              hipStream_t stream) {
  const float* group_emb = (const float*)d_in[0];
  const float* user_emb  = (const float*)d_in[1];
  const float* item_emb  = (const float*)d_in[2];
  const int* member_idx  = (const int*)d_in[3];
  const int* rui_rows = (const int*)d_in[4];
  const int* rui_cols = (const int*)d_in[5];
  const float* rui_vals = (const float*)d_in[6];
  const int* rgu_rows = (const int*)d_in[7];
  const int* rgu_cols = (const int*)d_in[8];
  const float* rgu_vals = (const float*)d_in[9];
  const int* rgi_rows = (const int*)d_in[10];
  const int* rgi_cols = (const int*)d_in[11];
  const float* rgi_vals = (const float*)d_in[12];
  const float* Wu = (const float*)d_in[13];
  const float* bu = (const float*)d_in[14];
  const float* Wi = (const float*)d_in[15];
  const float* bi = (const float*)d_in[16];
  const float* Wg = (const float*)d_in[17];
  const float* bg = (const float*)d_in[18];
  (void)in_sizes; (void)n_in; (void)out_size; (void)ws_size;

  float* part_cs = (float*)d_ws;                     // NCH*M f32
  short* sb = (short*)(part_cs + NCH * Mn);
  short* e_rui_u = sb;                 sb += (size_t)Un * Fd;
  short* e_rgu_u = sb;                 sb += (size_t)Un * Fd;
  short* e_rui_i = sb;                 sb += (size_t)In * Fd;
  short* e_rgi_i = sb;                 sb += (size_t)In * Fd;
  short* e_rgi_g = sb;                 sb += (size_t)Gn * Fd;
  short* e_rgu_g = sb;                 sb += (size_t)Gn * Fd;
  short* e_att_g = sb;                 sb += (size_t)Gn * Fd;
  short* att_item = sb;                sb += (size_t)In * Fd;
  short* user_bf = sb;                 sb += (size_t)Un * Fd;
  short* group_bf = sb;                sb += (size_t)Gn * Fd;
  short* item_bf = sb;                 sb += (size_t)In * Fd;
  short* members_bf = sb;              sb += (size_t)Mn * Fd;
  short* MT = sb;                      sb += (size_t)Fd * Mn;
  short* wu_bf = sb;                   sb += 5 * Fd * Fd;
  short* wi_bf = sb;                   sb += 5 * Fd * Fd;
  short* wg_bf = sb;                   sb += 5 * Fd * Fd;
  int* cnt    = (int*)sb;                            // CNT_TOT
  int* bsum   = cnt + CNT_TOT;                       // 6*64
  int* ptr    = bsum + 6 * 64;                       // CNT_TOT
  int* cursor = ptr + CNT_TOT;                       // CNT_TOT
  int2* packed = (int2*)(cursor + CNT_TOT);          // E_TOT

  // attention partial slabs alias d_out (fully overwritten by lin5 at the end)
  float* part_att = (float*)d_out;                   // NCH * I*F f32 (33.6 MB < 57.5 MB)

  // zero cnt (+bsum)
  {
    int nz = CNT_TOT + 6 * 64;
    int n4 = (nz + 3) / 4;  // may spill into ptr (overwritten later)
    zero_i4<<<(n4 + 255) / 256, 256, 0, stream>>>(cnt, n4);
  }

  // bf16 conversions (embeddings + weights)
  cvt_kernel<<<((int)((size_t)Un * Fd) + 255) / 256, 256, 0, stream>>>(user_emb, user_bf, Un * Fd);
  cvt_kernel<<<(Gn * Fd + 255) / 256, 256, 0, stream>>>(group_emb, group_bf, Gn * Fd);
  cvt_kernel<<<(In * Fd + 255) / 256, 256, 0, stream>>>(item_emb, item_bf, In * Fd);
  cvt_kernel<<<(5 * Fd * Fd + 255) / 256, 256, 0, stream>>>(Wu, wu_bf, 5 * Fd * Fd);
  cvt_kernel<<<(5 * Fd * Fd + 255) / 256, 256, 0, stream>>>(Wi, wi_bf, 5 * Fd * Fd);
  cvt_kernel<<<(5 * Fd * Fd + 255) / 256, 256, 0, stream>>>(Wg, wg_bf, 5 * Fd * Fd);
  gather_members<<<Mn, Fd, 0, stream>>>(user_bf, member_idx, members_bf);

  // histograms
  hist_kernel<<<(NNZ_RUI + 255) / 256, 256, 0, stream>>>(rui_rows, cnt + segoff(0), NNZ_RUI);
  hist_kernel<<<(NNZ_RUI + 255) / 256, 256, 0, stream>>>(rui_cols, cnt + segoff(1), NNZ_RUI);
  hist_kernel<<<(NNZ_RGU + 255) / 256, 256, 0, stream>>>(rgu_rows, cnt + segoff(2), NNZ_RGU);
  hist_kernel<<<(NNZ_RGU + 255) / 256, 256, 0, stream>>>(rgu_cols, cnt + segoff(3), NNZ_RGU);
  hist_kernel<<<(NNZ_RGI + 255) / 256, 256, 0, stream>>>(rgi_rows, cnt + segoff(4), NNZ_RGI);
  hist_kernel<<<(NNZ_RGI + 255) / 256, 256, 0, stream>>>(rgi_cols, cnt + segoff(5), NNZ_RGI);

  // batched exclusive scans -> row_ptr + cursor
  scanA<<<dim3(MAXNB, 6), 256, 0, stream>>>(cnt, ptr, bsum);
  scanB<<<6, 64, 0, stream>>>(bsum);
  scanC<<<dim3(MAXNB, 6), 256, 0, stream>>>(ptr, cursor, bsum);

  // scatter packed (gather_idx, val)
  scatter_kernel<<<(NNZ_RUI + 255) / 256, 256, 0, stream>>>(rui_rows, rui_cols, rui_vals, cursor + segoff(0), packed + eoff(0), NNZ_RUI);
  scatter_kernel<<<(NNZ_RUI + 255) / 256, 256, 0, stream>>>(rui_cols, rui_rows, rui_vals, cursor + segoff(1), packed + eoff(1), NNZ_RUI);
  scatter_kernel<<<(NNZ_RGU + 255) / 256, 256, 0, stream>>>(rgu_rows, rgu_cols, rgu_vals, cursor + segoff(2), packed + eoff(2), NNZ_RGU);
  scatter_kernel<<<(NNZ_RGU + 255) / 256, 256, 0, stream>>>(rgu_cols, rgu_rows, rgu_vals, cursor + segoff(3), packed + eoff(3), NNZ_RGU);
  scatter_kernel<<<(NNZ_RGI + 255) / 256, 256, 0, stream>>>(rgi_rows, rgi_cols, rgi_vals, cursor + segoff(4), packed + eoff(4), NNZ_RGI);
  scatter_kernel<<<(NNZ_RGI + 255) / 256, 256, 0, stream>>>(rgi_cols, rgi_rows, rgi_vals, cursor + segoff(5), packed + eoff(5), NNZ_RGI);

  // CSR SpMMs (bf16 in, bf16 out)
  spmm_csr_kernel<<<(Un + 3) / 4, 256, 0, stream>>>(ptr + segoff(0), packed + eoff(0), item_bf, e_rui_u, Un);
  spmm_csr_kernel<<<(Un + 3) / 4, 256, 0, stream>>>(ptr + segoff(3), packed + eoff(3), group_bf, e_rgu_u, Un);
  spmm_csr_kernel<<<(In + 3) / 4, 256, 0, stream>>>(ptr + segoff(1), packed + eoff(1), user_bf, e_rui_i, In);
  spmm_csr_kernel<<<(In + 3) / 4, 256, 0, stream>>>(ptr + segoff(5), packed + eoff(5), group_bf, e_rgi_i, In);
  spmm_csr_kernel<<<(Gn + 3) / 4, 256, 0, stream>>>(ptr + segoff(4), packed + eoff(4), item_bf, e_rgi_g, Gn);
  spmm_csr_kernel<<<(Gn + 3) / 4, 256, 0, stream>>>(ptr + segoff(2), packed + eoff(2), user_bf, e_rgu_g, Gn);

  // attention: partial colsum -> scaled transpose -> PV with global MT
  attn_colsum_kernel<<<dim3(Mn / 128, NCH), 256, 0, stream>>>(item_bf, members_bf, part_cs);
  mt_build<<<Mn / 64, 256, 0, stream>>>(members_bf, part_cs, MT);
  attn_out_kernel<<<dim3(In / 128, NCH), 256, 0, stream>>>(item_bf, members_bf, MT, part_att);
  reduce_mul_kernel<<<(In * Fd / 4) / 256, 256, 0, stream>>>(part_att, item_emb, att_item);
  spmm_csr_kernel<<<(Gn + 3) / 4, 256, 0, stream>>>(ptr + segoff(4), packed + eoff(4), att_item, e_att_g, Gn);

  // fused lin5 + LeakyReLU + L2 norm; output order: group | user | item
  float* out_g = (float*)d_out;
  float* out_u = out_g + (size_t)Gn * Fd;
  float* out_i = out_u + (size_t)Un * Fd;
  lin5_kernel<1><<<Gn / 128, 256, 0, stream>>>(group_bf, e_rgi_g, e_rgu_g, e_att_g, wg_bf, bg, out_g, Gn);
  lin5_kernel<0><<<(Un + 127) / 128, 256, 0, stream>>>(user_bf, e_rui_u, e_rgu_u, nullptr, wu_bf, bu, out_u, Un);
  lin5_kernel<0><<<In / 128, 256, 0, stream>>>(item_bf, e_rui_i, e_rgi_i, nullptr, wi_bf, bi, out_i, In);
}